// Round 5
// baseline (5209.114 us; speedup 1.0000x reference)
//
#include <hip/hip_runtime.h>
#include <hip/hip_bf16.h>

using bf16 = __hip_bfloat16;

static __device__ __forceinline__ float ldf(const float* p) { return *p; }
static __device__ __forceinline__ float ldf(const bf16* p) { return __bfloat162float(*p); }

// x: [64][3][132][132] fp32 -> xt: [132][132][3][64] fp32 (lane=batch innermost)
__global__ __launch_bounds__(256) void k_transpose_x(const float* __restrict__ x,
                                                     float* __restrict__ xt) {
  int idx = blockIdx.x * 256 + threadIdx.x;
  constexpr int N = 64 * 3 * 132 * 132;
  if (idx >= N) return;
  int w = idx % 132;
  int t = idx / 132;
  int h = t % 132;
  t /= 132;
  int c = t % 3;
  int b = t / 3;
  xt[((h * 132 + w) * 3 + c) * 64 + b] = x[idx];
}

// Stochastic strided conv. One output position per blockIdx.x, 40 output
// channels per block (4 waves x RL=10), lane = batch (64 = wavefront).
// EVERY cell is written with its exact reference value:
//   mask==1 : relu(conv + bias)
//   mask==0 : relu(bias)            (reference: where(mask,conv,0)+bias, relu)
// so downstream reads never see uninitialized memory regardless of mask logic.
template <int CIN, int COUT, int RL, typename TIN>
__global__ __launch_bounds__(256) void k_sconv(
    const TIN* __restrict__ in_t, int win,            // [win][win][CIN][64]
    const float* __restrict__ wgt,                    // [COUT][CIN][3][3] fp32
    const float* __restrict__ bias,                   // [COUT] fp32
    const int* __restrict__ selh, const int* __restrict__ selw,
    const int* __restrict__ mask,
    bf16* __restrict__ out_t, int ow) {               // [oh][ow][COUT][64]
  const int pos = blockIdx.x;
  const int b = threadIdx.x & 63;
  const int wv = threadIdx.x >> 6;
  const int o0 = __builtin_amdgcn_readfirstlane((int)(blockIdx.y * (4 * RL) + wv * RL));
  const size_t obase = ((size_t)pos * COUT + o0) * 64 + b;
  if (mask[pos] == 0) {
#pragma unroll
    for (int r = 0; r < RL; ++r) {
      float v = bias[o0 + r];
      out_t[obase + (size_t)r * 64] = __float2bfloat16(v > 0.f ? v : 0.f);
    }
    return;
  }
  const int y = pos / ow;
  const int x = pos % ow;
  const int ph = selh[pos] + 2 * y;
  const int pw = selw[pos] + 2 * x;
  const TIN* ip = in_t + ((size_t)(ph * win + pw) * CIN) * 64 + b;
  const float* wp0 = wgt + (size_t)o0 * CIN * 9;

  float acc[RL];
#pragma unroll
  for (int r = 0; r < RL; ++r) acc[r] = 0.f;

  for (int c = 0; c < CIN; ++c) {
    float v[9];
#pragma unroll
    for (int i = 0; i < 3; ++i)
#pragma unroll
      for (int j = 0; j < 3; ++j)
        v[i * 3 + j] = ldf(&ip[((size_t)(i * win + j) * CIN + c) * 64]);
    const float* wp = wp0 + c * 9;
#pragma unroll
    for (int r = 0; r < RL; ++r) {
#pragma unroll
      for (int t = 0; t < 9; ++t)
        acc[r] += v[t] * wp[(size_t)r * CIN * 9 + t];
    }
  }
#pragma unroll
  for (int r = 0; r < RL; ++r) {
    float v = acc[r] + bias[o0 + r];
    out_t[obase + (size_t)r * 64] = __float2bfloat16(v > 0.f ? v : 0.f);
  }
}

// Final dense 3x3 VALID conv, 10 output channels, no relu, fp32 out.
__global__ __launch_bounds__(256) void k_conv4(
    const float* __restrict__ in_t,   // [15][15][800][64] fp32
    const float* __restrict__ wgt,    // [10][800][3][3] fp32
    const float* __restrict__ bias,   // [10] fp32
    float* __restrict__ out) {        // [64][10][13][13] row-major fp32
  const int pos = blockIdx.x;         // 13*13
  const int y = pos / 13, x = pos % 13;
  const int b = threadIdx.x & 63;
  const int wv = __builtin_amdgcn_readfirstlane((int)(threadIdx.x >> 6));
  const float* ip = in_t + ((size_t)(y * 15 + x) * 800) * 64 + b;
  float acc[3] = {0.f, 0.f, 0.f};
  for (int c = 0; c < 800; ++c) {
    float v[9];
#pragma unroll
    for (int i = 0; i < 3; ++i)
#pragma unroll
      for (int j = 0; j < 3; ++j)
        v[i * 3 + j] = ip[((size_t)(i * 15 + j) * 800 + c) * 64];
#pragma unroll
    for (int r = 0; r < 3; ++r) {
      int o = wv + 4 * r;
      if (o < 10) {
        const float* wp = wgt + ((size_t)o * 800 + c) * 9;
#pragma unroll
        for (int t = 0; t < 9; ++t) acc[r] += v[t] * wp[t];
      }
    }
  }
#pragma unroll
  for (int r = 0; r < 3; ++r) {
    int o = wv + 4 * r;
    if (o < 10)
      out[(((size_t)b * 10 + o) * 13 + y) * 13 + x] = acc[r] + bias[o];
  }
}

// Layer-3 variant writing fp32 (its consumer is the dense conv).
template <int CIN, int COUT, int RL, typename TIN>
__global__ __launch_bounds__(256) void k_sconv_f32out(
    const TIN* __restrict__ in_t, int win,
    const float* __restrict__ wgt, const float* __restrict__ bias,
    const int* __restrict__ selh, const int* __restrict__ selw,
    const int* __restrict__ mask,
    float* __restrict__ out_t, int ow) {
  const int pos = blockIdx.x;
  const int b = threadIdx.x & 63;
  const int wv = threadIdx.x >> 6;
  const int o0 = __builtin_amdgcn_readfirstlane((int)(blockIdx.y * (4 * RL) + wv * RL));
  const size_t obase = ((size_t)pos * COUT + o0) * 64 + b;
  if (mask[pos] == 0) {
#pragma unroll
    for (int r = 0; r < RL; ++r) {
      float v = bias[o0 + r];
      out_t[obase + (size_t)r * 64] = v > 0.f ? v : 0.f;
    }
    return;
  }
  const int y = pos / ow;
  const int x = pos % ow;
  const int ph = selh[pos] + 2 * y;
  const int pw = selw[pos] + 2 * x;
  const TIN* ip = in_t + ((size_t)(ph * win + pw) * CIN) * 64 + b;
  const float* wp0 = wgt + (size_t)o0 * CIN * 9;
  float acc[RL];
#pragma unroll
  for (int r = 0; r < RL; ++r) acc[r] = 0.f;
  for (int c = 0; c < CIN; ++c) {
    float v[9];
#pragma unroll
    for (int i = 0; i < 3; ++i)
#pragma unroll
      for (int j = 0; j < 3; ++j)
        v[i * 3 + j] = ldf(&ip[((size_t)(i * win + j) * CIN + c) * 64]);
    const float* wp = wp0 + c * 9;
#pragma unroll
    for (int r = 0; r < RL; ++r) {
#pragma unroll
      for (int t = 0; t < 9; ++t)
        acc[r] += v[t] * wp[(size_t)r * CIN * 9 + t];
    }
  }
#pragma unroll
  for (int r = 0; r < RL; ++r) {
    float v = acc[r] + bias[o0 + r];
    out_t[obase + (size_t)r * 64] = v > 0.f ? v : 0.f;
  }
}

extern "C" void kernel_launch(void* const* d_in, const int* in_sizes, int n_in,
                              void* d_out, int out_size, void* d_ws, size_t ws_size,
                              hipStream_t stream) {
  // Inputs fp32 (reference dtype; confirmed: bf16-reads of weights NaN'd).
  // Output fp32 (reference dtype; this round's discriminating hypothesis).
  const float* x  = (const float*)d_in[0];
  const float* w1 = (const float*)d_in[1];
  const float* b1 = (const float*)d_in[2];
  const float* w2 = (const float*)d_in[3];
  const float* b2 = (const float*)d_in[4];
  const float* w3 = (const float*)d_in[5];
  const float* b3 = (const float*)d_in[6];
  const float* w4 = (const float*)d_in[7];
  const float* b4 = (const float*)d_in[8];
  const int* selh1 = (const int*)d_in[9];
  const int* selw1 = (const int*)d_in[10];
  const int* mask1 = (const int*)d_in[11];
  const int* selh2 = (const int*)d_in[12];
  const int* selw2 = (const int*)d_in[13];
  const int* mask2 = (const int*)d_in[14];
  const int* selh3 = (const int*)d_in[15];
  const int* selw3 = (const int*)d_in[16];
  const int* mask3 = (const int*)d_in[17];

  // Workspace (bytes), lifetimes overlapped; total 157,363,200 B (survived R4):
  //   o1t bf16 [65][65][200][64] = 108,160,000 B @ 0           (L1 w .. L2 r)
  //   xt  fp32 [132][132][3][64] =  13,381,632 B @ 108,160,000 (transp .. L1 r)
  //   o2t bf16 [31][31][400][64] =  49,203,200 B @ 108,160,000 (L2 w .. L3 r)
  //   o3t fp32 [15][15][800][64] =  46,080,000 B @ 0           (L3 w .. L4 r)
  char* ws = (char*)d_ws;
  bf16*  o1t = (bf16*)(ws);
  float* xt  = (float*)(ws + 108160000);
  bf16*  o2t = (bf16*)(ws + 108160000);
  float* o3t = (float*)(ws);

  k_transpose_x<<<dim3((64 * 3 * 132 * 132 + 255) / 256), dim3(256), 0, stream>>>(x, xt);

  // L1: (64,3,132,132) -> (65,65,200,64)
  k_sconv<3, 200, 10><<<dim3(65 * 65, 5), dim3(256), 0, stream>>>(
      xt, 132, w1, b1, selh1, selw1, mask1, o1t, 65);

  // L2: -> (31,31,400,64)
  k_sconv<200, 400, 10><<<dim3(31 * 31, 10), dim3(256), 0, stream>>>(
      o1t, 65, w2, b2, selh2, selw2, mask2, o2t, 31);

  // L3: -> (15,15,800,64) fp32
  k_sconv_f32out<400, 800, 10><<<dim3(15 * 15, 20), dim3(256), 0, stream>>>(
      o2t, 31, w3, b3, selh3, selw3, mask3, o3t, 15);

  // L4: dense 3x3 valid conv -> (64,10,13,13) flattened, fp32
  k_conv4<<<dim3(13 * 13), dim3(256), 0, stream>>>(o3t, w4, b4, (float*)d_out);
}

// Round 6
// 1261.152 us; speedup vs baseline: 4.1304x; 4.1304x over previous
//
#include <hip/hip_runtime.h>
#include <hip/hip_bf16.h>

using bf16 = __hip_bfloat16;
using short8 = __attribute__((ext_vector_type(8))) short;
using f32x4 = __attribute__((ext_vector_type(4))) float;

// Pre-packed A-operand (weights) in MFMA 16x16x32 frag order, module-scope so
// they don't consume d_ws (ws stays at the round-5-proven 157,363,200 B).
// Layout: [mtile16][ktile][lane64][8]  where m = mt*16 + (lane&15),
// k = kt*32 + (lane>>4)*8 + j.  Zero-padded for m>=COUT / k>=9*CIN.
__device__ __align__(16) bf16 g_wp1[16 * 3 * 512];    //  48 KB  (COUT 200->256, K 27->96,  CINP=8)
__device__ __align__(16) bf16 g_wp2[32 * 57 * 512];   // 1.9 MB  (COUT 400->512, K 1800->1824)
__device__ __align__(16) bf16 g_wp3[56 * 113 * 512];  // 6.5 MB  (COUT 800->896, K 3600->3616)

// ---------------- weight pack ----------------
template <int CIN, int CINP, int COUT, int KTILES>
__device__ __forceinline__ void pack_body(const float* __restrict__ w,
                                          bf16* __restrict__ dst, int total) {
  int el = blockIdx.x * 256 + threadIdx.x;
  if (el >= total) return;
  int j = el & 7;
  int lane = (el >> 3) & 63;
  int rest = el >> 9;
  int kt = rest % KTILES;
  int mt = rest / KTILES;
  int m = mt * 16 + (lane & 15);
  int k = kt * 32 + ((lane >> 4) * 8) + j;
  int chunk = k / CINP;
  int c = k - chunk * CINP;
  float val = 0.f;
  if (m < COUT && chunk < 9 && c < CIN)
    val = w[((size_t)m * CIN + c) * 9 + chunk];  // w[m][c][i][jj], chunk=i*3+jj
  dst[el] = __float2bfloat16(val);
}
__global__ __launch_bounds__(256) void k_pack1(const float* __restrict__ w) {
  pack_body<3, 8, 200, 3>(w, g_wp1, 16 * 3 * 512);
}
__global__ __launch_bounds__(256) void k_pack2(const float* __restrict__ w) {
  pack_body<200, 200, 400, 57>(w, g_wp2, 32 * 57 * 512);
}
__global__ __launch_bounds__(256) void k_pack3(const float* __restrict__ w) {
  pack_body<400, 400, 800, 113>(w, g_wp3, 56 * 113 * 512);
}

// x: [64][3][132][132] fp32 -> xt: [132][132][3][64] bf16
__global__ __launch_bounds__(256) void k_transpose_x(const float* __restrict__ x,
                                                     bf16* __restrict__ xt) {
  int idx = blockIdx.x * 256 + threadIdx.x;
  constexpr int N = 64 * 3 * 132 * 132;
  if (idx >= N) return;
  int w = idx % 132;
  int t = idx / 132;
  int h = t % 132;
  t /= 132;
  int c = t % 3;
  int b = t / 3;
  xt[((h * 132 + w) * 3 + c) * 64 + b] = __float2bfloat16(x[idx]);
}

// ---------------- MFMA stochastic strided conv ----------------
// GEMM per output position: M=COUT(wave:32, block:128), N=64(batch), K=9*CINP.
// B (patch) staged per K-step into LDS as [n][k-contig] (B^T), read ds_read_b128.
// A (weights) read directly from frag-packed global (coalesced 16B, L2-hot).
// Masked-off positions write relu(bias) (reference: where(mask,conv,0)+bias,relu).
template <int CIN, int CINP, int COUT, int WIN, int OW, int KTILES>
__device__ __forceinline__ void sconv_mfma_body(
    const bf16* __restrict__ in_t, const bf16* __restrict__ wp,
    const float* __restrict__ bias, const int* __restrict__ selh,
    const int* __restrict__ selw, const int* __restrict__ mask,
    bf16* __restrict__ out_t) {
  const int pos = blockIdx.x;
  const int tid = threadIdx.x;
  const int lane = tid & 63;
  const int wv = tid >> 6;
  __shared__ alignas(16) short Bs[64][40];  // [n][32k + 8 pad] bf16 bits
  f32x4 acc[2][4] = {};
  const bool on = (mask[pos] != 0);
  if (on) {
    const int y = pos / OW, xq = pos % OW;
    const int ph = selh[pos] + 2 * y;
    const int pw = selw[pos] + 2 * xq;
    const int sn = tid & 63;   // staging n (batch)
    const int skg = tid >> 6;  // staging k-group (8 k's)
    const short8* ap0 = reinterpret_cast<const short8*>(wp) +
                        ((size_t)(blockIdx.y * 8 + wv * 2) * KTILES) * 64 + lane;
    for (int kt = 0; kt < KTILES; ++kt) {
      int k = kt * 32 + skg * 8;
      int chunk = k / CINP;
      int c0 = k - chunk * CINP;
      if (chunk > 8) { chunk = 8; c0 = (CIN >= 8 ? CIN - 8 : 0); }  // pad-k: real reads x 0-weights
      const int di = (chunk * 342) >> 10;  // chunk/3 for chunk<9
      const int dj = chunk - di * 3;
      const unsigned short* bp =
          reinterpret_cast<const unsigned short*>(in_t) +
          (((size_t)(ph + di) * WIN + (pw + dj)) * CIN + c0) * 64 + sn;
      unsigned short v[8];
#pragma unroll
      for (int j = 0; j < 8; ++j) v[j] = bp[(size_t)j * 64];  // coalesced 128B/instr
      __syncthreads();  // previous tile fully consumed
      short8 pk;
#pragma unroll
      for (int j = 0; j < 8; ++j) pk[j] = (short)v[j];
      *reinterpret_cast<short8*>(&Bs[sn][skg * 8]) = pk;
      __syncthreads();
      short8 A0 = ap0[(size_t)kt * 64];
      short8 A1 = ap0[(size_t)(KTILES + kt) * 64];
      short8 Bf[4];
#pragma unroll
      for (int t = 0; t < 4; ++t)
        Bf[t] = *reinterpret_cast<const short8*>(&Bs[t * 16 + (lane & 15)][(lane >> 4) * 8]);
#pragma unroll
      for (int t = 0; t < 4; ++t) {
        acc[0][t] = __builtin_amdgcn_mfma_f32_16x16x32_bf16(A0, Bf[t], acc[0][t], 0, 0, 0);
        acc[1][t] = __builtin_amdgcn_mfma_f32_16x16x32_bf16(A1, Bf[t], acc[1][t], 0, 0, 0);
      }
    }
  }
  // epilogue: C/D layout col=lane&15 (n), row=(lane>>4)*4+reg (m)  [m89-verified]
  const int m0 = blockIdx.y * 128 + wv * 32;
  const int rowb = (lane >> 4) * 4;
  const int ncol = lane & 15;
#pragma unroll
  for (int ms = 0; ms < 2; ++ms) {
#pragma unroll
    for (int r = 0; r < 4; ++r) {
      const int cout = m0 + ms * 16 + rowb + r;
      if (cout < COUT) {
        const float bv = bias[cout];
#pragma unroll
        for (int t = 0; t < 4; ++t) {
          float vv = acc[ms][t][r] + bv;
          vv = vv > 0.f ? vv : 0.f;
          out_t[((size_t)pos * COUT + cout) * 64 + t * 16 + ncol] = __float2bfloat16(vv);
        }
      }
    }
  }
}

__global__ __launch_bounds__(256) void k_sconv1(
    const bf16* __restrict__ in_t, const float* __restrict__ bias,
    const int* __restrict__ selh, const int* __restrict__ selw,
    const int* __restrict__ mask, bf16* __restrict__ out_t) {
  sconv_mfma_body<3, 8, 200, 132, 65, 3>(in_t, g_wp1, bias, selh, selw, mask, out_t);
}
__global__ __launch_bounds__(256) void k_sconv2(
    const bf16* __restrict__ in_t, const float* __restrict__ bias,
    const int* __restrict__ selh, const int* __restrict__ selw,
    const int* __restrict__ mask, bf16* __restrict__ out_t) {
  sconv_mfma_body<200, 200, 400, 65, 31, 57>(in_t, g_wp2, bias, selh, selw, mask, out_t);
}
__global__ __launch_bounds__(256) void k_sconv3(
    const bf16* __restrict__ in_t, const float* __restrict__ bias,
    const int* __restrict__ selh, const int* __restrict__ selw,
    const int* __restrict__ mask, bf16* __restrict__ out_t) {
  sconv_mfma_body<400, 400, 800, 31, 15, 113>(in_t, g_wp3, bias, selh, selw, mask, out_t);
}

// Final dense 3x3 VALID conv, 10 outs, no relu, fp32 out (vector path, small).
__global__ __launch_bounds__(256) void k_conv4(
    const bf16* __restrict__ in_t,    // [15][15][800][64] bf16
    const float* __restrict__ wgt,    // [10][800][3][3] fp32
    const float* __restrict__ bias,   // [10] fp32
    float* __restrict__ out) {        // [64][10][13][13] fp32
  const int pos = blockIdx.x;         // 13*13
  const int y = pos / 13, x = pos % 13;
  const int b = threadIdx.x & 63;
  const int wv = __builtin_amdgcn_readfirstlane((int)(threadIdx.x >> 6));
  const bf16* ip = in_t + ((size_t)(y * 15 + x) * 800) * 64 + b;
  float acc[3] = {0.f, 0.f, 0.f};
  for (int c = 0; c < 800; ++c) {
    float v[9];
#pragma unroll
    for (int i = 0; i < 3; ++i)
#pragma unroll
      for (int j = 0; j < 3; ++j)
        v[i * 3 + j] = __bfloat162float(ip[((size_t)(i * 15 + j) * 800 + c) * 64]);
#pragma unroll
    for (int r = 0; r < 3; ++r) {
      int o = wv + 4 * r;
      if (o < 10) {
        const float* wpt = wgt + ((size_t)o * 800 + c) * 9;
#pragma unroll
        for (int t = 0; t < 9; ++t) acc[r] += v[t] * wpt[t];
      }
    }
  }
#pragma unroll
  for (int r = 0; r < 3; ++r) {
    int o = wv + 4 * r;
    if (o < 10)
      out[(((size_t)b * 10 + o) * 13 + y) * 13 + x] = acc[r] + bias[o];
  }
}

extern "C" void kernel_launch(void* const* d_in, const int* in_sizes, int n_in,
                              void* d_out, int out_size, void* d_ws, size_t ws_size,
                              hipStream_t stream) {
  const float* x  = (const float*)d_in[0];
  const float* w1 = (const float*)d_in[1];
  const float* b1 = (const float*)d_in[2];
  const float* w2 = (const float*)d_in[3];
  const float* b2 = (const float*)d_in[4];
  const float* w3 = (const float*)d_in[5];
  const float* b3 = (const float*)d_in[6];
  const float* w4 = (const float*)d_in[7];
  const float* b4 = (const float*)d_in[8];
  const int* selh1 = (const int*)d_in[9];
  const int* selw1 = (const int*)d_in[10];
  const int* mask1 = (const int*)d_in[11];
  const int* selh2 = (const int*)d_in[12];
  const int* selw2 = (const int*)d_in[13];
  const int* mask2 = (const int*)d_in[14];
  const int* selh3 = (const int*)d_in[15];
  const int* selw3 = (const int*)d_in[16];
  const int* mask3 = (const int*)d_in[17];

  // ws layout (bytes) == round-5-proven total 157,363,200:
  //   o1t bf16 [65][65][200][64] @ 0            (108,160,000 B; L1 w .. L2 r)
  //   xt  bf16 [132][132][3][64] @ 108,160,000  (6,691,840 B(+slack); transp .. L1 r)
  //   o2t bf16 [31][31][400][64] @ 108,160,000  (49,203,200 B; L2 w .. L3 r; xt dead)
  //   o3t bf16 [15][15][800][64] @ 0            (23,040,000 B; L3 w .. L4 r; o1t dead)
  // (L1's c-padding overreads xt by <=320 elems -> lands inside o2t slot: safe.)
  char* ws = (char*)d_ws;
  bf16* o1t = (bf16*)(ws);
  bf16* xt  = (bf16*)(ws + 108160000);
  bf16* o2t = (bf16*)(ws + 108160000);
  bf16* o3t = (bf16*)(ws);

  // weight packs (module-scope dst) + input transpose
  k_pack1<<<dim3((16 * 3 * 512 + 255) / 256), dim3(256), 0, stream>>>(w1);
  k_pack2<<<dim3((32 * 57 * 512 + 255) / 256), dim3(256), 0, stream>>>(w2);
  k_pack3<<<dim3((56 * 113 * 512 + 255) / 256), dim3(256), 0, stream>>>(w3);
  k_transpose_x<<<dim3((64 * 3 * 132 * 132 + 255) / 256), dim3(256), 0, stream>>>(x, xt);

  // L1: (132x132,3) -> (65x65,200);  M-pad 256 -> grid.y 2
  k_sconv1<<<dim3(65 * 65, 2), dim3(256), 0, stream>>>(xt, b1, selh1, selw1, mask1, o1t);
  // L2: -> (31x31,400); M-pad 512 -> grid.y 4
  k_sconv2<<<dim3(31 * 31, 4), dim3(256), 0, stream>>>(o1t, b2, selh2, selw2, mask2, o2t);
  // L3: -> (15x15,800); M-pad 896 -> grid.y 7
  k_sconv3<<<dim3(15 * 15, 7), dim3(256), 0, stream>>>(o2t, b3, selh3, selw3, mask3, o3t);
  // L4: dense 3x3 valid conv -> (64,10,13,13) fp32
  k_conv4<<<dim3(13 * 13), dim3(256), 0, stream>>>(o3t, w4, b4, (float*)d_out);
}

// Round 7
// 611.560 us; speedup vs baseline: 8.5178x; 2.0622x over previous
//
#include <hip/hip_runtime.h>
#include <hip/hip_bf16.h>

using bf16 = __hip_bfloat16;
using short8 = __attribute__((ext_vector_type(8))) short;
using f32x4 = __attribute__((ext_vector_type(4))) float;

// Pre-packed A-operand (weights) in MFMA 16x16x32 frag order, module-scope so
// they don't consume d_ws (ws stays at the round-5-proven 157,363,200 B).
// Layout: [mtile16][ktile][lane64][8]  where m = mt*16 + (lane&15),
// k = kt*32 + (lane>>4)*8 + j.  Zero-padded for m>=COUT / k>=9*CIN.
__device__ __align__(16) bf16 g_wp1[16 * 3 * 512];    //  48 KB  (COUT 200->256, K 27->96,  CINP=8)
__device__ __align__(16) bf16 g_wp2[32 * 57 * 512];   // 1.9 MB  (COUT 400->512, K 1800->1824)
__device__ __align__(16) bf16 g_wp3[56 * 113 * 512];  // 6.5 MB  (COUT 800->896, K 3600->3616)
__device__ __align__(16) bf16 g_wp4[1 * 225 * 512];   // 231 KB  (COUT 10->16,  K 7200 exact)

// ---------------- weight pack ----------------
template <int CIN, int CINP, int COUT, int KTILES>
__device__ __forceinline__ void pack_body(const float* __restrict__ w,
                                          bf16* __restrict__ dst, int total) {
  int el = blockIdx.x * 256 + threadIdx.x;
  if (el >= total) return;
  int j = el & 7;
  int lane = (el >> 3) & 63;
  int rest = el >> 9;
  int kt = rest % KTILES;
  int mt = rest / KTILES;
  int m = mt * 16 + (lane & 15);
  int k = kt * 32 + ((lane >> 4) * 8) + j;
  int chunk = k / CINP;
  int c = k - chunk * CINP;
  float val = 0.f;
  if (m < COUT && chunk < 9 && c < CIN)
    val = w[((size_t)m * CIN + c) * 9 + chunk];  // w[m][c][i][jj], chunk=i*3+jj
  dst[el] = __float2bfloat16(val);
}
__global__ __launch_bounds__(256) void k_pack1(const float* __restrict__ w) {
  pack_body<3, 8, 200, 3>(w, g_wp1, 16 * 3 * 512);
}
__global__ __launch_bounds__(256) void k_pack2(const float* __restrict__ w) {
  pack_body<200, 200, 400, 57>(w, g_wp2, 32 * 57 * 512);
}
__global__ __launch_bounds__(256) void k_pack3(const float* __restrict__ w) {
  pack_body<400, 400, 800, 113>(w, g_wp3, 56 * 113 * 512);
}
__global__ __launch_bounds__(256) void k_pack4(const float* __restrict__ w) {
  pack_body<800, 800, 10, 225>(w, g_wp4, 225 * 512);
}

// x: [64][3][132][132] fp32 -> xt: [132][132][3][64] bf16
__global__ __launch_bounds__(256) void k_transpose_x(const float* __restrict__ x,
                                                     bf16* __restrict__ xt) {
  int idx = blockIdx.x * 256 + threadIdx.x;
  constexpr int N = 64 * 3 * 132 * 132;
  if (idx >= N) return;
  int w = idx % 132;
  int t = idx / 132;
  int h = t % 132;
  t /= 132;
  int c = t % 3;
  int b = t / 3;
  xt[((h * 132 + w) * 3 + c) * 64 + b] = __float2bfloat16(x[idx]);
}

// ---------------- MFMA stochastic strided conv ----------------
// GEMM per output position: M=COUT(wave:32, block:128), N=64(batch), K=9*CINP.
// B (patch) staged per K-step into LDS as [n][k-contig] (B^T), read ds_read_b128.
// A (weights) read directly from frag-packed global (coalesced 16B, L2-hot).
// Masked-off positions write relu(bias) (reference: where(mask,conv,0)+bias,relu).
template <int CIN, int CINP, int COUT, int WIN, int OW, int KTILES>
__device__ __forceinline__ void sconv_mfma_body(
    const bf16* __restrict__ in_t, const bf16* __restrict__ wp,
    const float* __restrict__ bias, const int* __restrict__ selh,
    const int* __restrict__ selw, const int* __restrict__ mask,
    bf16* __restrict__ out_t) {
  const int pos = blockIdx.x;
  const int tid = threadIdx.x;
  const int lane = tid & 63;
  const int wv = tid >> 6;
  __shared__ alignas(16) short Bs[64][40];  // [n][32k + 8 pad] bf16 bits
  f32x4 acc[2][4] = {};
  const bool on = (mask[pos] != 0);
  if (on) {
    const int y = pos / OW, xq = pos % OW;
    const int ph = selh[pos] + 2 * y;
    const int pw = selw[pos] + 2 * xq;
    const int sn = tid & 63;   // staging n (batch)
    const int skg = tid >> 6;  // staging k-group (8 k's)
    const short8* ap0 = reinterpret_cast<const short8*>(wp) +
                        ((size_t)(blockIdx.y * 8 + wv * 2) * KTILES) * 64 + lane;
    for (int kt = 0; kt < KTILES; ++kt) {
      int k = kt * 32 + skg * 8;
      int chunk = k / CINP;
      int c0 = k - chunk * CINP;
      if (chunk > 8) { chunk = 8; c0 = (CIN >= 8 ? CIN - 8 : 0); }  // pad-k: real reads x 0-weights
      const int di = (chunk * 342) >> 10;  // chunk/3 for chunk<9
      const int dj = chunk - di * 3;
      const unsigned short* bp =
          reinterpret_cast<const unsigned short*>(in_t) +
          (((size_t)(ph + di) * WIN + (pw + dj)) * CIN + c0) * 64 + sn;
      unsigned short v[8];
#pragma unroll
      for (int j = 0; j < 8; ++j) v[j] = bp[(size_t)j * 64];  // coalesced 128B/instr
      __syncthreads();  // previous tile fully consumed
      short8 pk;
#pragma unroll
      for (int j = 0; j < 8; ++j) pk[j] = (short)v[j];
      *reinterpret_cast<short8*>(&Bs[sn][skg * 8]) = pk;
      __syncthreads();
      short8 A0 = ap0[(size_t)kt * 64];
      short8 A1 = ap0[(size_t)(KTILES + kt) * 64];
      short8 Bf[4];
#pragma unroll
      for (int t = 0; t < 4; ++t)
        Bf[t] = *reinterpret_cast<const short8*>(&Bs[t * 16 + (lane & 15)][(lane >> 4) * 8]);
#pragma unroll
      for (int t = 0; t < 4; ++t) {
        acc[0][t] = __builtin_amdgcn_mfma_f32_16x16x32_bf16(A0, Bf[t], acc[0][t], 0, 0, 0);
        acc[1][t] = __builtin_amdgcn_mfma_f32_16x16x32_bf16(A1, Bf[t], acc[1][t], 0, 0, 0);
      }
    }
  }
  // epilogue: C/D layout col=lane&15 (n), row=(lane>>4)*4+reg (m)  [m89-verified]
  const int m0 = blockIdx.y * 128 + wv * 32;
  const int rowb = (lane >> 4) * 4;
  const int ncol = lane & 15;
#pragma unroll
  for (int ms = 0; ms < 2; ++ms) {
#pragma unroll
    for (int r = 0; r < 4; ++r) {
      const int cout = m0 + ms * 16 + rowb + r;
      if (cout < COUT) {
        const float bv = bias[cout];
#pragma unroll
        for (int t = 0; t < 4; ++t) {
          float vv = acc[ms][t][r] + bv;
          vv = vv > 0.f ? vv : 0.f;
          out_t[((size_t)pos * COUT + cout) * 64 + t * 16 + ncol] = __float2bfloat16(vv);
        }
      }
    }
  }
}

__global__ __launch_bounds__(256) void k_sconv1(
    const bf16* __restrict__ in_t, const float* __restrict__ bias,
    const int* __restrict__ selh, const int* __restrict__ selw,
    const int* __restrict__ mask, bf16* __restrict__ out_t) {
  sconv_mfma_body<3, 8, 200, 132, 65, 3>(in_t, g_wp1, bias, selh, selw, mask, out_t);
}
__global__ __launch_bounds__(256) void k_sconv2(
    const bf16* __restrict__ in_t, const float* __restrict__ bias,
    const int* __restrict__ selh, const int* __restrict__ selw,
    const int* __restrict__ mask, bf16* __restrict__ out_t) {
  sconv_mfma_body<200, 200, 400, 65, 31, 57>(in_t, g_wp2, bias, selh, selw, mask, out_t);
}
__global__ __launch_bounds__(256) void k_sconv3(
    const bf16* __restrict__ in_t, const float* __restrict__ bias,
    const int* __restrict__ selh, const int* __restrict__ selw,
    const int* __restrict__ mask, bf16* __restrict__ out_t) {
  sconv_mfma_body<400, 400, 800, 31, 15, 113>(in_t, g_wp3, bias, selh, selw, mask, out_t);
}

// ---------------- L4: dense 3x3 VALID conv via MFMA ----------------
// Per position: M=16(pad of 10), N=64, K=7200 = 225 exact K-tiles (800=25*32,
// so chunk = kt/25 is constant within a tile). 4 waves K-split (kt = wv mod 4);
// each wave stages its own B-tile into a private LDS region and consumes it
// itself -> per-wave in-order DS pipe, NO barrier in the K-loop. One
// __syncthreads at the end for the cross-wave accumulator reduction.
__global__ __launch_bounds__(256) void k_conv4m(
    const bf16* __restrict__ in_t,   // [15][15][800][64] bf16
    const float* __restrict__ bias,  // [10] fp32
    float* __restrict__ out) {       // [64][10][13][13] fp32
  const int pos = blockIdx.x;        // 13*13
  const int y = pos / 13, x = pos % 13;
  const int tid = threadIdx.x;
  const int lane = tid & 63;
  const int wv = tid >> 6;
  __shared__ alignas(16) short Bs[4][64][40];  // per-wave [n][32k + 8 pad]
  __shared__ f32x4 Racc[4][4][64];             // cross-wave reduction
  f32x4 acc[4] = {};
  const short8* ap = reinterpret_cast<const short8*>(g_wp4);
  for (int kt = wv; kt < 225; kt += 4) {
    const int chunk = kt / 25;                 // 9 chunks x 25 tiles
    const int c0 = (kt - chunk * 25) * 32;
    const int di = chunk / 3, dj = chunk - di * 3;
    const unsigned short* bp =
        reinterpret_cast<const unsigned short*>(in_t) +
        (((size_t)(y + di) * 15 + (x + dj)) * 800 + c0) * 64 + lane;
    unsigned short v[32];
#pragma unroll
    for (int j = 0; j < 32; ++j) v[j] = bp[(size_t)j * 64];  // coalesced 128B/instr
#pragma unroll
    for (int q = 0; q < 4; ++q) {
      short8 pk;
#pragma unroll
      for (int j = 0; j < 8; ++j) pk[j] = (short)v[q * 8 + j];
      *reinterpret_cast<short8*>(&Bs[wv][lane][q * 8]) = pk;
    }
    short8 A0 = ap[(size_t)kt * 64 + lane];
    short8 Bf[4];
#pragma unroll
    for (int t = 0; t < 4; ++t)
      Bf[t] = *reinterpret_cast<const short8*>(
          &Bs[wv][t * 16 + (lane & 15)][(lane >> 4) * 8]);
#pragma unroll
    for (int t = 0; t < 4; ++t)
      acc[t] = __builtin_amdgcn_mfma_f32_16x16x32_bf16(A0, Bf[t], acc[t], 0, 0, 0);
  }
#pragma unroll
  for (int t = 0; t < 4; ++t) Racc[wv][t][lane] = acc[t];
  __syncthreads();
  if (wv == 0) {
    const int rowb = (lane >> 4) * 4;
    const int ncol = lane & 15;
#pragma unroll
    for (int t = 0; t < 4; ++t) {
      f32x4 s = Racc[0][t][lane];
#pragma unroll
      for (int w2 = 1; w2 < 4; ++w2) {
        f32x4 o = Racc[w2][t][lane];
#pragma unroll
        for (int r = 0; r < 4; ++r) s[r] += o[r];
      }
      const int n = t * 16 + ncol;
#pragma unroll
      for (int r = 0; r < 4; ++r) {
        const int m = rowb + r;
        if (m < 10)
          out[(((size_t)n * 10 + m) * 13 + y) * 13 + x] = s[r] + bias[m];
      }
    }
  }
}

extern "C" void kernel_launch(void* const* d_in, const int* in_sizes, int n_in,
                              void* d_out, int out_size, void* d_ws, size_t ws_size,
                              hipStream_t stream) {
  const float* x  = (const float*)d_in[0];
  const float* w1 = (const float*)d_in[1];
  const float* b1 = (const float*)d_in[2];
  const float* w2 = (const float*)d_in[3];
  const float* b2 = (const float*)d_in[4];
  const float* w3 = (const float*)d_in[5];
  const float* b3 = (const float*)d_in[6];
  const float* w4 = (const float*)d_in[7];
  const float* b4 = (const float*)d_in[8];
  const int* selh1 = (const int*)d_in[9];
  const int* selw1 = (const int*)d_in[10];
  const int* mask1 = (const int*)d_in[11];
  const int* selh2 = (const int*)d_in[12];
  const int* selw2 = (const int*)d_in[13];
  const int* mask2 = (const int*)d_in[14];
  const int* selh3 = (const int*)d_in[15];
  const int* selw3 = (const int*)d_in[16];
  const int* mask3 = (const int*)d_in[17];

  // ws layout (bytes) == round-5-proven total 157,363,200:
  //   o1t bf16 [65][65][200][64] @ 0            (108,160,000 B; L1 w .. L2 r)
  //   xt  bf16 [132][132][3][64] @ 108,160,000  (6,691,840 B(+slack); transp .. L1 r)
  //   o2t bf16 [31][31][400][64] @ 108,160,000  (49,203,200 B; L2 w .. L3 r; xt dead)
  //   o3t bf16 [15][15][800][64] @ 0            (23,040,000 B; L3 w .. L4 r; o1t dead)
  // (L1's c-padding overreads xt by <=320 elems -> lands inside o2t slot: safe.)
  char* ws = (char*)d_ws;
  bf16* o1t = (bf16*)(ws);
  bf16* xt  = (bf16*)(ws + 108160000);
  bf16* o2t = (bf16*)(ws + 108160000);
  bf16* o3t = (bf16*)(ws);

  // weight packs (module-scope dst) + input transpose
  k_pack1<<<dim3((16 * 3 * 512 + 255) / 256), dim3(256), 0, stream>>>(w1);
  k_pack2<<<dim3((32 * 57 * 512 + 255) / 256), dim3(256), 0, stream>>>(w2);
  k_pack3<<<dim3((56 * 113 * 512 + 255) / 256), dim3(256), 0, stream>>>(w3);
  k_pack4<<<dim3((225 * 512 + 255) / 256), dim3(256), 0, stream>>>(w4);
  k_transpose_x<<<dim3((64 * 3 * 132 * 132 + 255) / 256), dim3(256), 0, stream>>>(x, xt);

  // L1: (132x132,3) -> (65x65,200);  M-pad 256 -> grid.y 2
  k_sconv1<<<dim3(65 * 65, 2), dim3(256), 0, stream>>>(xt, b1, selh1, selw1, mask1, o1t);
  // L2: -> (31x31,400); M-pad 512 -> grid.y 4
  k_sconv2<<<dim3(31 * 31, 4), dim3(256), 0, stream>>>(o1t, b2, selh2, selw2, mask2, o2t);
  // L3: -> (15x15,800); M-pad 896 -> grid.y 7
  k_sconv3<<<dim3(15 * 15, 7), dim3(256), 0, stream>>>(o2t, b3, selh3, selw3, mask3, o3t);
  // L4: dense 3x3 valid conv via MFMA -> (64,10,13,13) fp32
  k_conv4m<<<dim3(13 * 13), dim3(256), 0, stream>>>(o3t, b4, (float*)d_out);
}